// Round 4
// baseline (421.355 us; speedup 1.0000x reference)
//
#include <hip/hip_runtime.h>
#include <cmath>

#define NC 6
#define CF 64
#define HH 88
#define WW 160
#define NPIX 14080     // 88*160
#define NVOX 200000
#define VPRE 64
#define VB 128         // voxels per block
#define NTH 1024       // threads per block (16 waves)
#define NWV 16

typedef unsigned int u32;

// ---------------- transpose [6][64][H*W] -> [6][H*W][64] (f32) ----------------
__global__ __launch_bounds__(256) void transpose_feats(const float* __restrict__ in,
                                                       float* __restrict__ out) {
    __shared__ float tile[64 * 65];
    int blk = blockIdx.x;            // 6 * 220
    int c = blk / 220;
    int p0 = (blk - c * 220) * 64;
    int tid = threadIdx.x;
    int lane = tid & 63;
    int quad = tid >> 6;
    for (int r = quad; r < 64; r += 4)
        tile[r * 65 + lane] = in[(c * 64 + r) * NPIX + p0 + lane];
    __syncthreads();
    for (int r = quad; r < 64; r += 4)
        out[((c * NPIX) + p0 + r) * 64 + lane] = tile[lane * 65 + r];
}

// ---------------- main fused kernel: one block = 128 voxels, 16 waves ----------------
__global__ __launch_bounds__(NTH, 4) void vox_main(
    const float* __restrict__ feats,
    const float* __restrict__ featT,
    const float* __restrict__ mask,
    const float* __restrict__ Kg,
    const float* __restrict__ ext,
    const float* __restrict__ wno,   // [64][65]
    const float* __restrict__ bno,   // [64]
    const float* __restrict__ wo,    // [64][130]
    const float* __restrict__ bo,    // [64]
    float* __restrict__ outp,        // [64][200000]
    int useT)
{
    __shared__ __align__(16) float s_wno[64 * 68];    // [o][c], row stride 68
    __shared__ __align__(16) float s_wo[64 * 132];    // [o][c'], c' = [f1|f2|d1|d2] remap
    __shared__ float s_b[128];
    __shared__ float s_ext[72];
    __shared__ float s_K[54];
    __shared__ __align__(16) float4 s_pair[NC * VB];  // x, y, depth, valid
    __shared__ __align__(16) float s_fbuf[NWV * 272]; // per-wave batch columns
    __shared__ float s_stage[64 * 129];               // [o][voxel], stride 129
    __shared__ u32 s_list1[VB], s_list2[VB];
    __shared__ int s_n1, s_n2;

    int tid = threadIdx.x;
    int lane = tid & 63;
    int wv = tid >> 6;
    int base = blockIdx.x * VB;

    if (tid == 0) { s_n1 = 0; s_n2 = 0; }
    if (tid < 64) s_b[tid] = bno[tid];
    else if (tid < 128) s_b[tid] = bo[tid - 64];
    if (tid >= 128 && tid < 200) {
        int i = tid - 128;
        s_ext[i] = ext[(i / 12) * 16 + (i % 12)];
    }
    if (tid >= 256 && tid < 310) {
        int i = tid - 256; int cam = i / 9; int e = i - cam * 9;
        s_K[i] = Kg[cam * 16 + (e / 3) * 4 + (e % 3)];
    }
    __syncthreads();

    // ---- phase 1: geometry, one lane per (cam, voxel) pair — EXACT r3 code ----
    if (tid < NC * VB) {
        #pragma clang fp contract(off)
        int cam = tid >> 7;
        int v = tid & (VB - 1);
        int n = base + v;
        if (n < NVOX) {
            int xi = n % 100;
            int t = n / 100;
            int yi = t % 100;
            int zi = t / 100;
            float X = -50.0f + (float)xi;
            float Y = -50.0f + (float)yi;
            float Z = -15.0f + 1.5f * (float)zi;
            const float* E = s_ext + cam * 12;
            const float* Kk = s_K + cam * 9;
            float vl0 = E[0]*X + E[1]*Y + E[2]*Z + E[3];
            float vl1 = E[4]*X + E[5]*Y + E[6]*Z + E[7];
            float vl2 = E[8]*X + E[9]*Y + E[10]*Z + E[11];
            float c0 = Kk[0]*vl0 + Kk[1]*vl1 + Kk[2]*vl2;
            float c1 = Kk[3]*vl0 + Kk[4]*vl1 + Kk[5]*vl2;
            float c2 = Kk[6]*vl0 + Kk[7]*vl1 + Kk[8]*vl2;
            float pz = c2 + 1e-8f;
            float px = c0 / pz;
            float py = c1 / pz;
            float gx = (px / 159.0f - 0.5f) * 2.0f;
            float gy = (py / 87.0f - 0.5f) * 2.0f;
            float x = ((gx + 1.0f) * 0.5f) * 159.0f;
            float y = ((gy + 1.0f) * 0.5f) * 87.0f;
            float xr = rintf(x), yr = rintf(y);
            bool nv = (xr >= 0.0f) && (xr <= 159.0f) && (yr >= 0.0f) && (yr <= 87.0f);
            float mval = 0.0f;
            if (nv) mval = mask[(cam * HH + (int)yr) * WW + (int)xr];
            bool ok = (mval > 0.5f) && (vl2 > 0.0f) &&
                      !((gx > 1.0f) || (gx < -1.0f) || (gy > 1.0f) || (gy < -1.0f));
            s_pair[cam * VB + v] = make_float4(x, y, vl2, ok ? 1.0f : 0.0f);
        } else {
            s_pair[cam * VB + v] = make_float4(0.0f, 0.0f, 0.0f, 0.0f);
        }
    }
    __syncthreads();

    // ---- phase 1.5: compaction into two lists ----
    if (tid < VB) {
        int v = tid;
        const float* pw = (const float*)s_pair;
        int cnt = 0, cam0 = 0, cam1 = 0;
        #pragma unroll
        for (int c = 0; c < NC; ++c) {
            float w = pw[(c * VB + v) * 4 + 3];
            if (w != 0.0f) { if (cnt == 0) cam0 = c; else if (cnt == 1) cam1 = c; ++cnt; }
        }
        if (cnt == 1) {
            int s = atomicAdd(&s_n1, 1);
            s_list1[s] = (u32)(v | (cam0 << 8));
        } else if (cnt == 2) {
            int s = atomicAdd(&s_n2, 1);
            s_list2[s] = (u32)(v | (cam0 << 8) | (cam1 << 12));
        }
    }
    // stage zero-init (always — output defaults to 0)
    for (int i = tid; i < 64 * 129; i += NTH) s_stage[i] = 0.0f;
    __syncthreads();

    int n1 = s_n1, n2 = s_n2;
    if ((n1 | n2) != 0) {                 // block-uniform: skip weight staging if empty
        for (int i = tid; i < 64 * 65; i += NTH)
            s_wno[(i / 65) * 68 + (i % 65)] = wno[i];
        for (int i = tid; i < 64 * 130; i += NTH) {
            int r = i / 130, c = i - r * 130;
            int cp = (c < 64) ? c : (c == 64 ? 128 : (c <= 128 ? c - 1 : 129));
            s_wo[r * 132 + cp] = wo[i];
        }
    }
    __syncthreads();

    float* fbw = s_fbuf + wv * 272;
    const float* fsrc = useT ? featT : feats;
    int A = useT ? 64 : 1;

    // ---- phase 2a: count==1 voxels, batches of 4 per wave ----
    for (int e0 = wv * 4; e0 < n1; e0 += NWV * 4) {
        float vals[4][4], wgt[4][4], dep[4];
        int vls[4]; bool act[4];
        #pragma unroll
        for (int j = 0; j < 4; ++j) {
            int e = e0 + j;
            act[j] = (e < n1);
            u32 ent = s_list1[act[j] ? e : e0];
            int v = ent & 127, c = (ent >> 8) & 7;
            vls[j] = v;
            float4 pd = s_pair[c * VB + v];
            float x = pd.x, y = pd.y;
            float x0f = floorf(x), y0f = floorf(y);
            float wx1 = x - x0f, wx0 = 1.0f - wx1;
            float wy1 = y - y0f, wy0 = 1.0f - wy1;
            float x1f = x0f + 1.0f, y1f = y0f + 1.0f;
            float bx0 = (x0f >= 0.0f && x0f <= 159.0f) ? 1.0f : 0.0f;
            float bx1 = (x1f >= 0.0f && x1f <= 159.0f) ? 1.0f : 0.0f;
            float by0 = (y0f >= 0.0f && y0f <= 87.0f) ? 1.0f : 0.0f;
            float by1 = (y1f >= 0.0f && y1f <= 87.0f) ? 1.0f : 0.0f;
            int ix0 = (int)fminf(fmaxf(x0f, 0.0f), 159.0f);
            int ix1 = (int)fminf(fmaxf(x1f, 0.0f), 159.0f);
            int iy0 = (int)fminf(fmaxf(y0f, 0.0f), 87.0f);
            int iy1 = (int)fminf(fmaxf(y1f, 0.0f), 87.0f);
            int Boff = useT ? (c * NPIX * 64 + lane) : ((c * 64 + lane) * NPIX);
            float am = act[j] ? 1.0f : 0.0f;
            wgt[j][0] = wx0 * wy0 * bx0 * by0 * am;
            wgt[j][1] = wx0 * wy1 * bx0 * by1 * am;
            wgt[j][2] = wx1 * wy0 * bx1 * by0 * am;
            wgt[j][3] = wx1 * wy1 * bx1 * by1 * am;
            vals[j][0] = fsrc[(iy0 * WW + ix0) * A + Boff];
            vals[j][1] = fsrc[(iy1 * WW + ix0) * A + Boff];
            vals[j][2] = fsrc[(iy0 * WW + ix1) * A + Boff];
            vals[j][3] = fsrc[(iy1 * WW + ix1) * A + Boff];
            dep[j] = pd.z / 100.0f;
        }
        #pragma unroll
        for (int j = 0; j < 4; ++j) {
            float fv;
            fv  = wgt[j][0] * vals[j][0];
            fv += wgt[j][1] * vals[j][1];
            fv += wgt[j][2] * vals[j][2];
            fv += wgt[j][3] * vals[j][3];
            fbw[j * 68 + lane] = fv;
            if (lane == 0) fbw[j * 68 + 64] = dep[j];
        }
        asm volatile("s_waitcnt lgkmcnt(0)" ::: "memory");
        float a0 = s_b[lane], a1 = s_b[lane], a2 = s_b[lane], a3 = s_b[lane];
        const float* wr = s_wno + lane * 68;
        #pragma unroll
        for (int ch = 0; ch < 64; ch += 4) {
            float4 w4 = *(const float4*)(wr + ch);           // one weight read, 4 voxels
            float4 f0 = *(const float4*)(fbw + 0 * 68 + ch); // uniform -> broadcast
            float4 f1 = *(const float4*)(fbw + 1 * 68 + ch);
            float4 f2 = *(const float4*)(fbw + 2 * 68 + ch);
            float4 f3 = *(const float4*)(fbw + 3 * 68 + ch);
            a0 += w4.x*f0.x; a0 += w4.y*f0.y; a0 += w4.z*f0.z; a0 += w4.w*f0.w;
            a1 += w4.x*f1.x; a1 += w4.y*f1.y; a1 += w4.z*f1.z; a1 += w4.w*f1.w;
            a2 += w4.x*f2.x; a2 += w4.y*f2.y; a2 += w4.z*f2.z; a2 += w4.w*f2.w;
            a3 += w4.x*f3.x; a3 += w4.y*f3.y; a3 += w4.z*f3.z; a3 += w4.w*f3.w;
        }
        float wd = wr[64];
        float av[4];
        av[0] = a0 + wd * fbw[0 * 68 + 64];
        av[1] = a1 + wd * fbw[1 * 68 + 64];
        av[2] = a2 + wd * fbw[2 * 68 + 64];
        av[3] = a3 + wd * fbw[3 * 68 + 64];
        #pragma unroll
        for (int j = 0; j < 4; ++j) {
            float acc = av[j];
            float r = acc > 0.0f ? acc : expm1f(acc);
            if (act[j]) s_stage[lane * 129 + vls[j]] = r;   // stride 129: conflict-free
        }
    }

    // ---- phase 2b: count==2 voxels, batches of 2 per wave ----
    for (int e0 = wv * 2; e0 < n2; e0 += NWV * 2) {
        float vals[2][2][4], wgt[2][2][4], dg[2][2];
        int vls[2], grp[2][2]; bool act[2];
        #pragma unroll
        for (int j = 0; j < 2; ++j) {
            int e = e0 + j;
            act[j] = (e < n2);
            u32 ent = s_list2[act[j] ? e : e0];
            int v = ent & 127;
            int cams[2] = { (int)((ent >> 8) & 15), (int)((ent >> 12) & 15) };
            vls[j] = v;
            #pragma unroll
            for (int k = 0; k < 2; ++k) {
                int c = cams[k];
                grp[j][k] = (c == 1 || c == 2 || c == 5) ? 1 : 0;
                float4 pd = s_pair[c * VB + v];
                float x = pd.x, y = pd.y;
                float x0f = floorf(x), y0f = floorf(y);
                float wx1 = x - x0f, wx0 = 1.0f - wx1;
                float wy1 = y - y0f, wy0 = 1.0f - wy1;
                float x1f = x0f + 1.0f, y1f = y0f + 1.0f;
                float bx0 = (x0f >= 0.0f && x0f <= 159.0f) ? 1.0f : 0.0f;
                float bx1 = (x1f >= 0.0f && x1f <= 159.0f) ? 1.0f : 0.0f;
                float by0 = (y0f >= 0.0f && y0f <= 87.0f) ? 1.0f : 0.0f;
                float by1 = (y1f >= 0.0f && y1f <= 87.0f) ? 1.0f : 0.0f;
                int ix0 = (int)fminf(fmaxf(x0f, 0.0f), 159.0f);
                int ix1 = (int)fminf(fmaxf(x1f, 0.0f), 159.0f);
                int iy0 = (int)fminf(fmaxf(y0f, 0.0f), 87.0f);
                int iy1 = (int)fminf(fmaxf(y1f, 0.0f), 87.0f);
                int Boff = useT ? (c * NPIX * 64 + lane) : ((c * 64 + lane) * NPIX);
                float am = act[j] ? 1.0f : 0.0f;
                wgt[j][k][0] = wx0 * wy0 * bx0 * by0 * am;
                wgt[j][k][1] = wx0 * wy1 * bx0 * by1 * am;
                wgt[j][k][2] = wx1 * wy0 * bx1 * by0 * am;
                wgt[j][k][3] = wx1 * wy1 * bx1 * by1 * am;
                vals[j][k][0] = fsrc[(iy0 * WW + ix0) * A + Boff];
                vals[j][k][1] = fsrc[(iy1 * WW + ix0) * A + Boff];
                vals[j][k][2] = fsrc[(iy0 * WW + ix1) * A + Boff];
                vals[j][k][3] = fsrc[(iy1 * WW + ix1) * A + Boff];
                dg[j][k] = pd.z / 100.0f;
            }
        }
        #pragma unroll
        for (int j = 0; j < 2; ++j) {
            float fg0 = 0.0f, fg1 = 0.0f, dd0 = 0.0f, dd1 = 0.0f;
            #pragma unroll
            for (int k = 0; k < 2; ++k) {
                float fv;
                fv  = wgt[j][k][0] * vals[j][k][0];
                fv += wgt[j][k][1] * vals[j][k][1];
                fv += wgt[j][k][2] * vals[j][k][2];
                fv += wgt[j][k][3] * vals[j][k][3];
                if (grp[j][k]) { fg1 += fv; dd1 += dg[j][k]; }
                else           { fg0 += fv; dd0 += dg[j][k]; }
            }
            fbw[j * 132 + lane] = fg0;        // layout [f1 | f2 | d1 | d2]
            fbw[j * 132 + 64 + lane] = fg1;
            if (lane == 0) { fbw[j * 132 + 128] = dd0; fbw[j * 132 + 129] = dd1; }
        }
        asm volatile("s_waitcnt lgkmcnt(0)" ::: "memory");
        float a0 = s_b[64 + lane], a1 = s_b[64 + lane];
        const float* wr = s_wo + lane * 132;
        #pragma unroll
        for (int ch = 0; ch < 128; ch += 4) {
            float4 w4 = *(const float4*)(wr + ch);
            float4 f0 = *(const float4*)(fbw + 0 * 132 + ch);
            float4 f1 = *(const float4*)(fbw + 1 * 132 + ch);
            a0 += w4.x*f0.x; a0 += w4.y*f0.y; a0 += w4.z*f0.z; a0 += w4.w*f0.w;
            a1 += w4.x*f1.x; a1 += w4.y*f1.y; a1 += w4.z*f1.z; a1 += w4.w*f1.w;
        }
        float wd0 = wr[128], wd1 = wr[129];
        a0 += wd0 * fbw[0 * 132 + 128]; a0 += wd1 * fbw[0 * 132 + 129];
        a1 += wd0 * fbw[1 * 132 + 128]; a1 += wd1 * fbw[1 * 132 + 129];
        float av[2] = { a0, a1 };
        #pragma unroll
        for (int j = 0; j < 2; ++j) {
            float acc = av[j];
            float r = acc > 0.0f ? acc : expm1f(acc);
            if (act[j]) s_stage[lane * 129 + vls[j]] = r;
        }
    }
    __syncthreads();

    // ---- phase 3: coalesced store, 2 chunks of 64 voxels ----
    for (int j = 0; j < 2; ++j) {
        int cb = base + j * 64;
        if (cb + lane < NVOX) {
            #pragma unroll
            for (int r4 = 0; r4 < 4; ++r4) {
                int r = wv * 4 + r4;
                outp[(size_t)r * NVOX + cb + lane] = s_stage[r * 129 + j * 64 + lane];
            }
        }
    }
}

extern "C" void kernel_launch(void* const* d_in, const int* in_sizes, int n_in,
                              void* d_out, int out_size, void* d_ws, size_t ws_size,
                              hipStream_t stream) {
    const float* feats = (const float*)d_in[0];
    const float* mask  = (const float*)d_in[1];
    const float* Kg    = (const float*)d_in[2];
    const float* ext   = (const float*)d_in[3];
    const float* wno   = (const float*)d_in[4];
    const float* bno   = (const float*)d_in[5];
    const float* wo    = (const float*)d_in[6];
    const float* bo    = (const float*)d_in[7];
    float* outp = (float*)d_out;
    float* featT = (float*)d_ws;

    size_t need = (size_t)NC * CF * NPIX * sizeof(float);   // 21.6 MB
    int useT = (ws_size >= need) ? 1 : 0;
    if (useT) {
        transpose_feats<<<NC * 220, 256, 0, stream>>>(feats, featT);
    }
    int nblk = (NVOX + VB - 1) / VB;                        // 1563
    vox_main<<<nblk, NTH, 0, stream>>>(feats, featT, mask, Kg, ext,
                                       wno, bno, wo, bo, outp, useT);
}

// Round 5
// 170.881 us; speedup vs baseline: 2.4658x; 2.4658x over previous
//
#include <hip/hip_runtime.h>
#include <cmath>

#define NC 6
#define CF 64
#define HH 88
#define WW 160
#define NPIX 14080     // 88*160
#define NVOX 200000
#define VPRE 64
#define VB 128         // voxels per block
#define NTH 512        // 8 waves
#define NWV 8

typedef unsigned int u32;

// ---------------- transpose [6][64][H*W] -> [6][H*W][64] (f32) ----------------
__global__ __launch_bounds__(256) void transpose_feats(const float* __restrict__ in,
                                                       float* __restrict__ out) {
    __shared__ float tile[64 * 65];
    int blk = blockIdx.x;            // 6 * 220
    int c = blk / 220;
    int p0 = (blk - c * 220) * 64;
    int tid = threadIdx.x;
    int lane = tid & 63;
    int quad = tid >> 6;
    for (int r = quad; r < 64; r += 4)
        tile[r * 65 + lane] = in[(c * 64 + r) * NPIX + p0 + lane];
    __syncthreads();
    for (int r = quad; r < 64; r += 4)
        out[((c * NPIX) + p0 + r) * 64 + lane] = tile[lane * 65 + r];
}

__device__ __forceinline__ float elu1(float x) { return x > 0.0f ? x : expm1f(x); }

// bilinear gather: voxel uniform across wave, lane = channel. Math identical to r3.
__device__ __forceinline__ float gather_bilin(const float* __restrict__ fsrc, int useT,
                                              int lane, int cam, float x, float y) {
    float x0f = floorf(x), y0f = floorf(y);
    float wx1 = x - x0f, wx0 = 1.0f - wx1;
    float wy1 = y - y0f, wy0 = 1.0f - wy1;
    float x1f = x0f + 1.0f, y1f = y0f + 1.0f;
    float bx0 = (x0f >= 0.0f && x0f <= 159.0f) ? 1.0f : 0.0f;
    float bx1 = (x1f >= 0.0f && x1f <= 159.0f) ? 1.0f : 0.0f;
    float by0 = (y0f >= 0.0f && y0f <= 87.0f) ? 1.0f : 0.0f;
    float by1 = (y1f >= 0.0f && y1f <= 87.0f) ? 1.0f : 0.0f;
    int ix0 = (int)fminf(fmaxf(x0f, 0.0f), 159.0f);
    int ix1 = (int)fminf(fmaxf(x1f, 0.0f), 159.0f);
    int iy0 = (int)fminf(fmaxf(y0f, 0.0f), 87.0f);
    int iy1 = (int)fminf(fmaxf(y1f, 0.0f), 87.0f);
    int A = useT ? 64 : 1;
    int Boff = useT ? (cam * NPIX * 64 + lane) : ((cam * 64 + lane) * NPIX);
    float v00 = fsrc[(iy0 * WW + ix0) * A + Boff];   // 4 coalesced 256B loads in flight
    float v01 = fsrc[(iy1 * WW + ix0) * A + Boff];
    float v10 = fsrc[(iy0 * WW + ix1) * A + Boff];
    float v11 = fsrc[(iy1 * WW + ix1) * A + Boff];
    float fv;                                        // reference corner order
    fv  = (wx0 * wy0 * bx0 * by0) * v00;
    fv += (wx0 * wy1 * bx0 * by1) * v01;
    fv += (wx1 * wy0 * bx1 * by0) * v10;
    fv += (wx1 * wy1 * bx1 * by1) * v11;
    return fv;
}

// 8-output FMA step over 4 channels, weights via wave-uniform scalar loads
#define FMA8_STEP(W0,W1,W2,W3,W4,W5,W6,W7,CG,F0,F1,F2,F3) \
    a0 += W0[CG]*F0; a0 += W0[CG+1]*F1; a0 += W0[CG+2]*F2; a0 += W0[CG+3]*F3; \
    a1 += W1[CG]*F0; a1 += W1[CG+1]*F1; a1 += W1[CG+2]*F2; a1 += W1[CG+3]*F3; \
    a2 += W2[CG]*F0; a2 += W2[CG+1]*F1; a2 += W2[CG+2]*F2; a2 += W2[CG+3]*F3; \
    a3 += W3[CG]*F0; a3 += W3[CG+1]*F1; a3 += W3[CG+2]*F2; a3 += W3[CG+3]*F3; \
    a4 += W4[CG]*F0; a4 += W4[CG+1]*F1; a4 += W4[CG+2]*F2; a4 += W4[CG+3]*F3; \
    a5 += W5[CG]*F0; a5 += W5[CG+1]*F1; a5 += W5[CG+2]*F2; a5 += W5[CG+3]*F3; \
    a6 += W6[CG]*F0; a6 += W6[CG+1]*F1; a6 += W6[CG+2]*F2; a6 += W6[CG+3]*F3; \
    a7 += W7[CG]*F0; a7 += W7[CG+1]*F1; a7 += W7[CG+2]*F2; a7 += W7[CG+3]*F3;

// ---------------- main fused kernel: one block = 128 voxels, 8 waves ----------------
__global__ __launch_bounds__(NTH, 4) void vox_main(
    const float* __restrict__ feats,
    const float* __restrict__ featT,
    const float* __restrict__ mask,
    const float* __restrict__ Kg,
    const float* __restrict__ ext,
    const float* __restrict__ wno,   // [64][65]
    const float* __restrict__ bno,   // [64]
    const float* __restrict__ wo,    // [64][130]
    const float* __restrict__ bo,    // [64]
    float* __restrict__ outp,        // [64][200000]
    int useT)
{
    __shared__ float s_ext[72];
    __shared__ float s_K[54];
    __shared__ __align__(16) float4 s_pair[NC * VB];  // x, y, depth, valid
    __shared__ float s_F[65 * 66];                    // [channel][entry], stride 66
    __shared__ float s_stage[64 * 129];               // [o][voxel], stride 129
    __shared__ u32 s_list1[VB], s_list2[VB];
    __shared__ int s_n1, s_n2;

    int tid = threadIdx.x;
    int lane = tid & 63;
    int wv = tid >> 6;                // 0..7
    int base = blockIdx.x * VB;

    if (tid == 0) { s_n1 = 0; s_n2 = 0; }
    if (tid >= 64 && tid < 136) {
        int i = tid - 64;
        s_ext[i] = ext[(i / 12) * 16 + (i % 12)];
    }
    if (tid >= 192 && tid < 246) {
        int i = tid - 192; int cam = i / 9; int e = i - cam * 9;
        s_K[i] = Kg[cam * 16 + (e / 3) * 4 + (e % 3)];
    }
    __syncthreads();

    // ---- phase 1: geometry (EXACT r3 code), 768 pairs over 512 threads ----
    for (int p = tid; p < NC * VB; p += NTH) {
        #pragma clang fp contract(off)
        int cam = p >> 7;
        int v = p & (VB - 1);
        int n = base + v;
        if (n < NVOX) {
            int xi = n % 100;
            int t = n / 100;
            int yi = t % 100;
            int zi = t / 100;
            float X = -50.0f + (float)xi;
            float Y = -50.0f + (float)yi;
            float Z = -15.0f + 1.5f * (float)zi;
            const float* E = s_ext + cam * 12;
            const float* Kk = s_K + cam * 9;
            float vl0 = E[0]*X + E[1]*Y + E[2]*Z + E[3];
            float vl1 = E[4]*X + E[5]*Y + E[6]*Z + E[7];
            float vl2 = E[8]*X + E[9]*Y + E[10]*Z + E[11];
            float c0 = Kk[0]*vl0 + Kk[1]*vl1 + Kk[2]*vl2;
            float c1 = Kk[3]*vl0 + Kk[4]*vl1 + Kk[5]*vl2;
            float c2 = Kk[6]*vl0 + Kk[7]*vl1 + Kk[8]*vl2;
            float pz = c2 + 1e-8f;
            float px = c0 / pz;
            float py = c1 / pz;
            float gx = (px / 159.0f - 0.5f) * 2.0f;
            float gy = (py / 87.0f - 0.5f) * 2.0f;
            float x = ((gx + 1.0f) * 0.5f) * 159.0f;
            float y = ((gy + 1.0f) * 0.5f) * 87.0f;
            float xr = rintf(x), yr = rintf(y);
            bool nv = (xr >= 0.0f) && (xr <= 159.0f) && (yr >= 0.0f) && (yr <= 87.0f);
            float mval = 0.0f;
            if (nv) mval = mask[(cam * HH + (int)yr) * WW + (int)xr];
            bool ok = (mval > 0.5f) && (vl2 > 0.0f) &&
                      !((gx > 1.0f) || (gx < -1.0f) || (gy > 1.0f) || (gy < -1.0f));
            s_pair[cam * VB + v] = make_float4(x, y, vl2, ok ? 1.0f : 0.0f);
        } else {
            s_pair[cam * VB + v] = make_float4(0.0f, 0.0f, 0.0f, 0.0f);
        }
    }
    __syncthreads();

    // ---- phase 1.5: compaction + stage zero-init ----
    if (tid < VB) {
        int v = tid;
        const float* pw = (const float*)s_pair;
        int cnt = 0, cam0 = 0, cam1 = 0;
        #pragma unroll
        for (int c = 0; c < NC; ++c) {
            float w = pw[(c * VB + v) * 4 + 3];
            if (w != 0.0f) { if (cnt == 0) cam0 = c; else if (cnt == 1) cam1 = c; ++cnt; }
        }
        if (cnt == 1) {
            int s = atomicAdd(&s_n1, 1);
            s_list1[s] = (u32)(v | (cam0 << 8));
        } else if (cnt == 2) {
            int s = atomicAdd(&s_n2, 1);
            s_list2[s] = (u32)(v | (cam0 << 8) | (cam1 << 12));
        }
    }
    for (int i = tid; i < 64 * 129; i += NTH) s_stage[i] = 0.0f;
    __syncthreads();

    int n1 = s_n1, n2 = s_n2;
    const float* fsrc = useT ? featT : feats;
    int wvu = __builtin_amdgcn_readfirstlane(wv);
    int obase = wvu * 8;
    const float* w0n = wno + (obase + 0) * 65;
    const float* w1n = wno + (obase + 1) * 65;
    const float* w2n = wno + (obase + 2) * 65;
    const float* w3n = wno + (obase + 3) * 65;
    const float* w4n = wno + (obase + 4) * 65;
    const float* w5n = wno + (obase + 5) * 65;
    const float* w6n = wno + (obase + 6) * 65;
    const float* w7n = wno + (obase + 7) * 65;
    const float* w0o = wo + (obase + 0) * 130;
    const float* w1o = wo + (obase + 1) * 130;
    const float* w2o = wo + (obase + 2) * 130;
    const float* w3o = wo + (obase + 3) * 130;
    const float* w4o = wo + (obase + 4) * 130;
    const float* w5o = wo + (obase + 5) * 130;
    const float* w6o = wo + (obase + 6) * 130;
    const float* w7o = wo + (obase + 7) * 130;

    // ---- count==1 tiles ----
    for (int t0 = 0; t0 < n1; t0 += 64) {
        int tl = min(64, n1 - t0);
        // gather: wave per entry
        for (int e = wv; e < tl; e += NWV) {
            u32 ent = s_list1[t0 + e];
            int v = ent & 127, c = (ent >> 8) & 7;
            float4 pd = s_pair[c * VB + v];
            float fv = gather_bilin(fsrc, useT, lane, c, pd.x, pd.y);
            s_F[lane * 66 + e] = fv;
            if (lane == 0) s_F[64 * 66 + e] = pd.z / 100.0f;
        }
        __syncthreads();
        // compute: lane = entry, 8 outputs per wave, uniform scalar weights
        float a0 = bno[obase + 0], a1 = bno[obase + 1], a2 = bno[obase + 2], a3 = bno[obase + 3];
        float a4 = bno[obase + 4], a5 = bno[obase + 5], a6 = bno[obase + 6], a7 = bno[obase + 7];
        for (int cg = 0; cg < 64; cg += 4) {
            float f0 = s_F[(cg + 0) * 66 + lane];
            float f1 = s_F[(cg + 1) * 66 + lane];
            float f2 = s_F[(cg + 2) * 66 + lane];
            float f3 = s_F[(cg + 3) * 66 + lane];
            FMA8_STEP(w0n, w1n, w2n, w3n, w4n, w5n, w6n, w7n, cg, f0, f1, f2, f3)
        }
        float fd = s_F[64 * 66 + lane];
        a0 += w0n[64] * fd; a1 += w1n[64] * fd; a2 += w2n[64] * fd; a3 += w3n[64] * fd;
        a4 += w4n[64] * fd; a5 += w5n[64] * fd; a6 += w6n[64] * fd; a7 += w7n[64] * fd;
        if (lane < tl) {
            int vv = (int)(s_list1[t0 + lane] & 127);
            s_stage[(obase + 0) * 129 + vv] = elu1(a0);
            s_stage[(obase + 1) * 129 + vv] = elu1(a1);
            s_stage[(obase + 2) * 129 + vv] = elu1(a2);
            s_stage[(obase + 3) * 129 + vv] = elu1(a3);
            s_stage[(obase + 4) * 129 + vv] = elu1(a4);
            s_stage[(obase + 5) * 129 + vv] = elu1(a5);
            s_stage[(obase + 6) * 129 + vv] = elu1(a6);
            s_stage[(obase + 7) * 129 + vv] = elu1(a7);
        }
        __syncthreads();   // F reusable
    }

    // ---- count==2 tiles: two passes over the same 65-row F tile ----
    for (int t0 = 0; t0 < n2; t0 += 64) {
        int tl = min(64, n2 - t0);
        // gather pass A: group-1 cams {0,3,4}
        for (int e = wv; e < tl; e += NWV) {
            u32 ent = s_list2[t0 + e];
            int v = ent & 127;
            int c0 = (ent >> 8) & 15, c1 = (ent >> 12) & 15;
            float fg = 0.0f, dd = 0.0f;
            if (!(c0 == 1 || c0 == 2 || c0 == 5)) {
                float4 pd = s_pair[c0 * VB + v];
                fg += gather_bilin(fsrc, useT, lane, c0, pd.x, pd.y);
                dd += pd.z / 100.0f;
            }
            if (!(c1 == 1 || c1 == 2 || c1 == 5)) {
                float4 pd = s_pair[c1 * VB + v];
                fg += gather_bilin(fsrc, useT, lane, c1, pd.x, pd.y);
                dd += pd.z / 100.0f;
            }
            s_F[lane * 66 + e] = fg;
            if (lane == 0) s_F[64 * 66 + e] = dd;
        }
        __syncthreads();
        // compute pass A: wo columns 0..63 (f1) + 64 (d1)
        float a0 = bo[obase + 0], a1 = bo[obase + 1], a2 = bo[obase + 2], a3 = bo[obase + 3];
        float a4 = bo[obase + 4], a5 = bo[obase + 5], a6 = bo[obase + 6], a7 = bo[obase + 7];
        for (int cg = 0; cg < 64; cg += 4) {
            float f0 = s_F[(cg + 0) * 66 + lane];
            float f1 = s_F[(cg + 1) * 66 + lane];
            float f2 = s_F[(cg + 2) * 66 + lane];
            float f3 = s_F[(cg + 3) * 66 + lane];
            FMA8_STEP(w0o, w1o, w2o, w3o, w4o, w5o, w6o, w7o, cg, f0, f1, f2, f3)
        }
        {
            float fd = s_F[64 * 66 + lane];
            a0 += w0o[64] * fd; a1 += w1o[64] * fd; a2 += w2o[64] * fd; a3 += w3o[64] * fd;
            a4 += w4o[64] * fd; a5 += w5o[64] * fd; a6 += w6o[64] * fd; a7 += w7o[64] * fd;
        }
        __syncthreads();   // done reading F
        // gather pass B: group-2 cams {1,2,5}
        for (int e = wv; e < tl; e += NWV) {
            u32 ent = s_list2[t0 + e];
            int v = ent & 127;
            int c0 = (ent >> 8) & 15, c1 = (ent >> 12) & 15;
            float fg = 0.0f, dd = 0.0f;
            if (c0 == 1 || c0 == 2 || c0 == 5) {
                float4 pd = s_pair[c0 * VB + v];
                fg += gather_bilin(fsrc, useT, lane, c0, pd.x, pd.y);
                dd += pd.z / 100.0f;
            }
            if (c1 == 1 || c1 == 2 || c1 == 5) {
                float4 pd = s_pair[c1 * VB + v];
                fg += gather_bilin(fsrc, useT, lane, c1, pd.x, pd.y);
                dd += pd.z / 100.0f;
            }
            s_F[lane * 66 + e] = fg;
            if (lane == 0) s_F[64 * 66 + e] = dd;
        }
        __syncthreads();
        // compute pass B: wo columns 65..128 (f2) + 129 (d2)
        for (int cg = 0; cg < 64; cg += 4) {
            float f0 = s_F[(cg + 0) * 66 + lane];
            float f1 = s_F[(cg + 1) * 66 + lane];
            float f2 = s_F[(cg + 2) * 66 + lane];
            float f3 = s_F[(cg + 3) * 66 + lane];
            int cgo = cg + 65;
            FMA8_STEP(w0o, w1o, w2o, w3o, w4o, w5o, w6o, w7o, cgo, f0, f1, f2, f3)
        }
        {
            float fd = s_F[64 * 66 + lane];
            a0 += w0o[129] * fd; a1 += w1o[129] * fd; a2 += w2o[129] * fd; a3 += w3o[129] * fd;
            a4 += w4o[129] * fd; a5 += w5o[129] * fd; a6 += w6o[129] * fd; a7 += w7o[129] * fd;
        }
        if (lane < tl) {
            int vv = (int)(s_list2[t0 + lane] & 127);
            s_stage[(obase + 0) * 129 + vv] = elu1(a0);
            s_stage[(obase + 1) * 129 + vv] = elu1(a1);
            s_stage[(obase + 2) * 129 + vv] = elu1(a2);
            s_stage[(obase + 3) * 129 + vv] = elu1(a3);
            s_stage[(obase + 4) * 129 + vv] = elu1(a4);
            s_stage[(obase + 5) * 129 + vv] = elu1(a5);
            s_stage[(obase + 6) * 129 + vv] = elu1(a6);
            s_stage[(obase + 7) * 129 + vv] = elu1(a7);
        }
        __syncthreads();
    }
    __syncthreads();

    // ---- phase 3: coalesced store, 64 rows x 2 chunks of 64 voxels ----
    for (int j = 0; j < 2; ++j) {
        int cb = base + j * 64;
        if (cb + lane < NVOX) {
            #pragma unroll
            for (int r8 = 0; r8 < 8; ++r8) {
                int r = wv * 8 + r8;
                outp[(size_t)r * NVOX + cb + lane] = s_stage[r * 129 + j * 64 + lane];
            }
        }
    }
}

extern "C" void kernel_launch(void* const* d_in, const int* in_sizes, int n_in,
                              void* d_out, int out_size, void* d_ws, size_t ws_size,
                              hipStream_t stream) {
    const float* feats = (const float*)d_in[0];
    const float* mask  = (const float*)d_in[1];
    const float* Kg    = (const float*)d_in[2];
    const float* ext   = (const float*)d_in[3];
    const float* wno   = (const float*)d_in[4];
    const float* bno   = (const float*)d_in[5];
    const float* wo    = (const float*)d_in[6];
    const float* bo    = (const float*)d_in[7];
    float* outp = (float*)d_out;
    float* featT = (float*)d_ws;

    size_t need = (size_t)NC * CF * NPIX * sizeof(float);   // 21.6 MB
    int useT = (ws_size >= need) ? 1 : 0;
    if (useT) {
        transpose_feats<<<NC * 220, 256, 0, stream>>>(feats, featT);
    }
    int nblk = (NVOX + VB - 1) / VB;                        // 1563
    vox_main<<<nblk, NTH, 0, stream>>>(feats, featT, mask, Kg, ext,
                                       wno, bno, wo, bo, outp, useT);
}

// Round 6
// 165.844 us; speedup vs baseline: 2.5407x; 1.0304x over previous
//
#include <hip/hip_runtime.h>
#include <cmath>

#define NC 6
#define CF 64
#define HH 88
#define WW 160
#define NPIX 14080     // 88*160
#define NVOX 200000
#define VPRE 64
#define VB 128         // voxels per block
#define NTH 512        // 8 waves
#define NWV 8

typedef unsigned int u32;

// ---------------- zero-fill output ----------------
__global__ __launch_bounds__(256) void zfill(float4* __restrict__ out, int n4) {
    int i = blockIdx.x * 256 + threadIdx.x;
    int stride = gridDim.x * 256;
    for (; i < n4; i += stride) out[i] = make_float4(0.f, 0.f, 0.f, 0.f);
}

// ---------------- transpose [6][64][H*W] -> [6][H*W][64] (f32) ----------------
__global__ __launch_bounds__(256) void transpose_feats(const float* __restrict__ in,
                                                       float* __restrict__ out) {
    __shared__ float tile[64 * 65];
    int blk = blockIdx.x;            // 6 * 220
    int c = blk / 220;
    int p0 = (blk - c * 220) * 64;
    int tid = threadIdx.x;
    int lane = tid & 63;
    int quad = tid >> 6;
    for (int r = quad; r < 64; r += 4)
        tile[r * 65 + lane] = in[(c * 64 + r) * NPIX + p0 + lane];
    __syncthreads();
    for (int r = quad; r < 64; r += 4)
        out[((c * NPIX) + p0 + r) * 64 + lane] = tile[lane * 65 + r];
}

__device__ __forceinline__ float elu1(float x) { return x > 0.0f ? x : expm1f(x); }

// bilinear gather: voxel uniform across wave, lane = channel. Math identical to r3/r5.
__device__ __forceinline__ float gather_bilin(const float* __restrict__ fsrc, int useT,
                                              int lane, int cam, float x, float y) {
    float x0f = floorf(x), y0f = floorf(y);
    float wx1 = x - x0f, wx0 = 1.0f - wx1;
    float wy1 = y - y0f, wy0 = 1.0f - wy1;
    float x1f = x0f + 1.0f, y1f = y0f + 1.0f;
    float bx0 = (x0f >= 0.0f && x0f <= 159.0f) ? 1.0f : 0.0f;
    float bx1 = (x1f >= 0.0f && x1f <= 159.0f) ? 1.0f : 0.0f;
    float by0 = (y0f >= 0.0f && y0f <= 87.0f) ? 1.0f : 0.0f;
    float by1 = (y1f >= 0.0f && y1f <= 87.0f) ? 1.0f : 0.0f;
    int ix0 = (int)fminf(fmaxf(x0f, 0.0f), 159.0f);
    int ix1 = (int)fminf(fmaxf(x1f, 0.0f), 159.0f);
    int iy0 = (int)fminf(fmaxf(y0f, 0.0f), 87.0f);
    int iy1 = (int)fminf(fmaxf(y1f, 0.0f), 87.0f);
    int A = useT ? 64 : 1;
    int Boff = useT ? (cam * NPIX * 64 + lane) : ((cam * 64 + lane) * NPIX);
    float v00 = fsrc[(iy0 * WW + ix0) * A + Boff];
    float v01 = fsrc[(iy1 * WW + ix0) * A + Boff];
    float v10 = fsrc[(iy0 * WW + ix1) * A + Boff];
    float v11 = fsrc[(iy1 * WW + ix1) * A + Boff];
    float fv;                                        // reference corner order
    fv  = (wx0 * wy0 * bx0 * by0) * v00;
    fv += (wx0 * wy1 * bx0 * by1) * v01;
    fv += (wx1 * wy0 * bx1 * by0) * v10;
    fv += (wx1 * wy1 * bx1 * by1) * v11;
    return fv;
}

// 8-output FMA step over 4 channels, weights via wave-uniform scalar loads
#define FMA8_STEP(W0,W1,W2,W3,W4,W5,W6,W7,CG,F0,F1,F2,F3) \
    a0 += W0[CG]*F0; a0 += W0[CG+1]*F1; a0 += W0[CG+2]*F2; a0 += W0[CG+3]*F3; \
    a1 += W1[CG]*F0; a1 += W1[CG+1]*F1; a1 += W1[CG+2]*F2; a1 += W1[CG+3]*F3; \
    a2 += W2[CG]*F0; a2 += W2[CG+1]*F1; a2 += W2[CG+2]*F2; a2 += W2[CG+3]*F3; \
    a3 += W3[CG]*F0; a3 += W3[CG+1]*F1; a3 += W3[CG+2]*F2; a3 += W3[CG+3]*F3; \
    a4 += W4[CG]*F0; a4 += W4[CG+1]*F1; a4 += W4[CG+2]*F2; a4 += W4[CG+3]*F3; \
    a5 += W5[CG]*F0; a5 += W5[CG+1]*F1; a5 += W5[CG+2]*F2; a5 += W5[CG+3]*F3; \
    a6 += W6[CG]*F0; a6 += W6[CG+1]*F1; a6 += W6[CG+2]*F2; a6 += W6[CG+3]*F3; \
    a7 += W7[CG]*F0; a7 += W7[CG+1]*F1; a7 += W7[CG+2]*F2; a7 += W7[CG+3]*F3;

// ---------------- main fused kernel: one block = 128 voxels, 8 waves ----------------
__global__ __launch_bounds__(NTH, 4) void vox_main(
    const float* __restrict__ feats,
    const float* __restrict__ featT,
    const float* __restrict__ mask,
    const float* __restrict__ Kg,
    const float* __restrict__ ext,
    const float* __restrict__ wno,   // [64][65]
    const float* __restrict__ bno,   // [64]
    const float* __restrict__ wo,    // [64][130]
    const float* __restrict__ bo,    // [64]
    float* __restrict__ outp,        // [64][200000], pre-zeroed
    int useT)
{
    __shared__ float s_ext[72];
    __shared__ float s_K[54];
    __shared__ __align__(16) float4 s_pair[NC * VB];  // x, y, depth, valid
    __shared__ float s_F[65 * 66];                    // [channel][entry], stride 66
    __shared__ u32 s_list1[VB], s_list2[VB];
    __shared__ int s_n1, s_n2;

    int tid = threadIdx.x;
    int lane = tid & 63;
    int wv = tid >> 6;                // 0..7
    int base = blockIdx.x * VB;

    if (tid == 0) { s_n1 = 0; s_n2 = 0; }
    if (tid >= 64 && tid < 136) {
        int i = tid - 64;
        s_ext[i] = ext[(i / 12) * 16 + (i % 12)];
    }
    if (tid >= 192 && tid < 246) {
        int i = tid - 192; int cam = i / 9; int e = i - cam * 9;
        s_K[i] = Kg[cam * 16 + (e / 3) * 4 + (e % 3)];
    }
    __syncthreads();

    // ---- phase 1: geometry (EXACT r3/r5 code) ----
    for (int p = tid; p < NC * VB; p += NTH) {
        #pragma clang fp contract(off)
        int cam = p >> 7;
        int v = p & (VB - 1);
        int n = base + v;
        if (n < NVOX) {
            int xi = n % 100;
            int t = n / 100;
            int yi = t % 100;
            int zi = t / 100;
            float X = -50.0f + (float)xi;
            float Y = -50.0f + (float)yi;
            float Z = -15.0f + 1.5f * (float)zi;
            const float* E = s_ext + cam * 12;
            const float* Kk = s_K + cam * 9;
            float vl0 = E[0]*X + E[1]*Y + E[2]*Z + E[3];
            float vl1 = E[4]*X + E[5]*Y + E[6]*Z + E[7];
            float vl2 = E[8]*X + E[9]*Y + E[10]*Z + E[11];
            float c0 = Kk[0]*vl0 + Kk[1]*vl1 + Kk[2]*vl2;
            float c1 = Kk[3]*vl0 + Kk[4]*vl1 + Kk[5]*vl2;
            float c2 = Kk[6]*vl0 + Kk[7]*vl1 + Kk[8]*vl2;
            float pz = c2 + 1e-8f;
            float px = c0 / pz;
            float py = c1 / pz;
            float gx = (px / 159.0f - 0.5f) * 2.0f;
            float gy = (py / 87.0f - 0.5f) * 2.0f;
            float x = ((gx + 1.0f) * 0.5f) * 159.0f;
            float y = ((gy + 1.0f) * 0.5f) * 87.0f;
            float xr = rintf(x), yr = rintf(y);
            bool nv = (xr >= 0.0f) && (xr <= 159.0f) && (yr >= 0.0f) && (yr <= 87.0f);
            float mval = 0.0f;
            if (nv) mval = mask[(cam * HH + (int)yr) * WW + (int)xr];
            bool ok = (mval > 0.5f) && (vl2 > 0.0f) &&
                      !((gx > 1.0f) || (gx < -1.0f) || (gy > 1.0f) || (gy < -1.0f));
            s_pair[cam * VB + v] = make_float4(x, y, vl2, ok ? 1.0f : 0.0f);
        } else {
            s_pair[cam * VB + v] = make_float4(0.0f, 0.0f, 0.0f, 0.0f);
        }
    }
    __syncthreads();

    // ---- phase 1.5: compaction ----
    if (tid < VB) {
        int v = tid;
        const float* pw = (const float*)s_pair;
        int cnt = 0, cam0 = 0, cam1 = 0;
        #pragma unroll
        for (int c = 0; c < NC; ++c) {
            float w = pw[(c * VB + v) * 4 + 3];
            if (w != 0.0f) { if (cnt == 0) cam0 = c; else if (cnt == 1) cam1 = c; ++cnt; }
        }
        if (cnt == 1) {
            int s = atomicAdd(&s_n1, 1);
            s_list1[s] = (u32)(v | (cam0 << 8));
        } else if (cnt == 2) {
            int s = atomicAdd(&s_n2, 1);
            s_list2[s] = (u32)(v | (cam0 << 8) | (cam1 << 12));
        }
    }
    __syncthreads();

    int n1 = s_n1, n2 = s_n2;
    const float* fsrc = useT ? featT : feats;
    int wvu = __builtin_amdgcn_readfirstlane(wv);
    int obase = wvu * 8;
    const float* w0n = wno + (obase + 0) * 65;
    const float* w1n = wno + (obase + 1) * 65;
    const float* w2n = wno + (obase + 2) * 65;
    const float* w3n = wno + (obase + 3) * 65;
    const float* w4n = wno + (obase + 4) * 65;
    const float* w5n = wno + (obase + 5) * 65;
    const float* w6n = wno + (obase + 6) * 65;
    const float* w7n = wno + (obase + 7) * 65;
    const float* w0o = wo + (obase + 0) * 130;
    const float* w1o = wo + (obase + 1) * 130;
    const float* w2o = wo + (obase + 2) * 130;
    const float* w3o = wo + (obase + 3) * 130;
    const float* w4o = wo + (obase + 4) * 130;
    const float* w5o = wo + (obase + 5) * 130;
    const float* w6o = wo + (obase + 6) * 130;
    const float* w7o = wo + (obase + 7) * 130;

    // ---- count==1 tiles ----
    for (int t0 = 0; t0 < n1; t0 += 64) {
        int tl = min(64, n1 - t0);
        for (int e = wv; e < tl; e += NWV) {
            u32 ent = s_list1[t0 + e];
            int v = ent & 127, c = (ent >> 8) & 7;
            float4 pd = s_pair[c * VB + v];
            float fv = gather_bilin(fsrc, useT, lane, c, pd.x, pd.y);
            s_F[lane * 66 + e] = fv;
            if (lane == 0) s_F[64 * 66 + e] = pd.z / 100.0f;
        }
        __syncthreads();
        float a0 = bno[obase + 0], a1 = bno[obase + 1], a2 = bno[obase + 2], a3 = bno[obase + 3];
        float a4 = bno[obase + 4], a5 = bno[obase + 5], a6 = bno[obase + 6], a7 = bno[obase + 7];
        for (int cg = 0; cg < 64; cg += 4) {
            float f0 = s_F[(cg + 0) * 66 + lane];
            float f1 = s_F[(cg + 1) * 66 + lane];
            float f2 = s_F[(cg + 2) * 66 + lane];
            float f3 = s_F[(cg + 3) * 66 + lane];
            FMA8_STEP(w0n, w1n, w2n, w3n, w4n, w5n, w6n, w7n, cg, f0, f1, f2, f3)
        }
        float fd = s_F[64 * 66 + lane];
        a0 += w0n[64] * fd; a1 += w1n[64] * fd; a2 += w2n[64] * fd; a3 += w3n[64] * fd;
        a4 += w4n[64] * fd; a5 += w5n[64] * fd; a6 += w6n[64] * fd; a7 += w7n[64] * fd;
        if (lane < tl) {
            size_t col = (size_t)(base + (int)(s_list1[t0 + lane] & 127));
            outp[(size_t)(obase + 0) * NVOX + col] = elu1(a0);
            outp[(size_t)(obase + 1) * NVOX + col] = elu1(a1);
            outp[(size_t)(obase + 2) * NVOX + col] = elu1(a2);
            outp[(size_t)(obase + 3) * NVOX + col] = elu1(a3);
            outp[(size_t)(obase + 4) * NVOX + col] = elu1(a4);
            outp[(size_t)(obase + 5) * NVOX + col] = elu1(a5);
            outp[(size_t)(obase + 6) * NVOX + col] = elu1(a6);
            outp[(size_t)(obase + 7) * NVOX + col] = elu1(a7);
        }
        __syncthreads();   // F reusable
    }

    // ---- count==2 tiles: two passes over the same 65-row F tile ----
    for (int t0 = 0; t0 < n2; t0 += 64) {
        int tl = min(64, n2 - t0);
        for (int e = wv; e < tl; e += NWV) {      // pass A gather: cams {0,3,4}
            u32 ent = s_list2[t0 + e];
            int v = ent & 127;
            int c0 = (ent >> 8) & 15, c1 = (ent >> 12) & 15;
            float fg = 0.0f, dd = 0.0f;
            if (!(c0 == 1 || c0 == 2 || c0 == 5)) {
                float4 pd = s_pair[c0 * VB + v];
                fg += gather_bilin(fsrc, useT, lane, c0, pd.x, pd.y);
                dd += pd.z / 100.0f;
            }
            if (!(c1 == 1 || c1 == 2 || c1 == 5)) {
                float4 pd = s_pair[c1 * VB + v];
                fg += gather_bilin(fsrc, useT, lane, c1, pd.x, pd.y);
                dd += pd.z / 100.0f;
            }
            s_F[lane * 66 + e] = fg;
            if (lane == 0) s_F[64 * 66 + e] = dd;
        }
        __syncthreads();
        float a0 = bo[obase + 0], a1 = bo[obase + 1], a2 = bo[obase + 2], a3 = bo[obase + 3];
        float a4 = bo[obase + 4], a5 = bo[obase + 5], a6 = bo[obase + 6], a7 = bo[obase + 7];
        for (int cg = 0; cg < 64; cg += 4) {      // pass A compute: cols 0..64
            float f0 = s_F[(cg + 0) * 66 + lane];
            float f1 = s_F[(cg + 1) * 66 + lane];
            float f2 = s_F[(cg + 2) * 66 + lane];
            float f3 = s_F[(cg + 3) * 66 + lane];
            FMA8_STEP(w0o, w1o, w2o, w3o, w4o, w5o, w6o, w7o, cg, f0, f1, f2, f3)
        }
        {
            float fd = s_F[64 * 66 + lane];
            a0 += w0o[64] * fd; a1 += w1o[64] * fd; a2 += w2o[64] * fd; a3 += w3o[64] * fd;
            a4 += w4o[64] * fd; a5 += w5o[64] * fd; a6 += w6o[64] * fd; a7 += w7o[64] * fd;
        }
        __syncthreads();
        for (int e = wv; e < tl; e += NWV) {      // pass B gather: cams {1,2,5}
            u32 ent = s_list2[t0 + e];
            int v = ent & 127;
            int c0 = (ent >> 8) & 15, c1 = (ent >> 12) & 15;
            float fg = 0.0f, dd = 0.0f;
            if (c0 == 1 || c0 == 2 || c0 == 5) {
                float4 pd = s_pair[c0 * VB + v];
                fg += gather_bilin(fsrc, useT, lane, c0, pd.x, pd.y);
                dd += pd.z / 100.0f;
            }
            if (c1 == 1 || c1 == 2 || c1 == 5) {
                float4 pd = s_pair[c1 * VB + v];
                fg += gather_bilin(fsrc, useT, lane, c1, pd.x, pd.y);
                dd += pd.z / 100.0f;
            }
            s_F[lane * 66 + e] = fg;
            if (lane == 0) s_F[64 * 66 + e] = dd;
        }
        __syncthreads();
        for (int cg = 0; cg < 64; cg += 4) {      // pass B compute: cols 65..129
            float f0 = s_F[(cg + 0) * 66 + lane];
            float f1 = s_F[(cg + 1) * 66 + lane];
            float f2 = s_F[(cg + 2) * 66 + lane];
            float f3 = s_F[(cg + 3) * 66 + lane];
            int cgo = cg + 65;
            FMA8_STEP(w0o, w1o, w2o, w3o, w4o, w5o, w6o, w7o, cgo, f0, f1, f2, f3)
        }
        {
            float fd = s_F[64 * 66 + lane];
            a0 += w0o[129] * fd; a1 += w1o[129] * fd; a2 += w2o[129] * fd; a3 += w3o[129] * fd;
            a4 += w4o[129] * fd; a5 += w5o[129] * fd; a6 += w6o[129] * fd; a7 += w7o[129] * fd;
        }
        if (lane < tl) {
            size_t col = (size_t)(base + (int)(s_list2[t0 + lane] & 127));
            outp[(size_t)(obase + 0) * NVOX + col] = elu1(a0);
            outp[(size_t)(obase + 1) * NVOX + col] = elu1(a1);
            outp[(size_t)(obase + 2) * NVOX + col] = elu1(a2);
            outp[(size_t)(obase + 3) * NVOX + col] = elu1(a3);
            outp[(size_t)(obase + 4) * NVOX + col] = elu1(a4);
            outp[(size_t)(obase + 5) * NVOX + col] = elu1(a5);
            outp[(size_t)(obase + 6) * NVOX + col] = elu1(a6);
            outp[(size_t)(obase + 7) * NVOX + col] = elu1(a7);
        }
        __syncthreads();
    }
}

extern "C" void kernel_launch(void* const* d_in, const int* in_sizes, int n_in,
                              void* d_out, int out_size, void* d_ws, size_t ws_size,
                              hipStream_t stream) {
    const float* feats = (const float*)d_in[0];
    const float* mask  = (const float*)d_in[1];
    const float* Kg    = (const float*)d_in[2];
    const float* ext   = (const float*)d_in[3];
    const float* wno   = (const float*)d_in[4];
    const float* bno   = (const float*)d_in[5];
    const float* wo    = (const float*)d_in[6];
    const float* bo    = (const float*)d_in[7];
    float* outp = (float*)d_out;
    float* featT = (float*)d_ws;

    int n4 = out_size / 4;                                  // out_size = 12.8M floats
    zfill<<<2048, 256, 0, stream>>>((float4*)d_out, n4);

    size_t need = (size_t)NC * CF * NPIX * sizeof(float);   // 21.6 MB
    int useT = (ws_size >= need) ? 1 : 0;
    if (useT) {
        transpose_feats<<<NC * 220, 256, 0, stream>>>(feats, featT);
    }
    int nblk = (NVOX + VB - 1) / VB;                        // 1563
    vox_main<<<nblk, NTH, 0, stream>>>(feats, featT, mask, Kg, ext,
                                       wno, bno, wo, bo, outp, useT);
}